// Round 11
// baseline (465.880 us; speedup 1.0000x reference)
//
#include <hip/hip_runtime.h>
#include <hip/hip_fp16.h>
#include <stdint.h>

#define B_TOT 131072
#define CHUNK 65536
#define NH 16
#define NC 32
#define HIDD 512

typedef unsigned short u16;
typedef unsigned int u32;
typedef __attribute__((ext_vector_type(8))) short short8;
typedef __attribute__((ext_vector_type(4))) float f32x4;
typedef __attribute__((ext_vector_type(4))) int i32x4;

#define GLLDS(g, l) __builtin_amdgcn_global_load_lds((const __attribute__((address_space(1))) unsigned int*)(g), (__attribute__((address_space(3))) unsigned int*)(l), 16, 0, 0)

__device__ __forceinline__ u16 f2bf(float x){
  unsigned u = __float_as_uint(x);
  u += 0x7fffu + ((u >> 16) & 1u);
  return (u16)(u >> 16);
}
__device__ __forceinline__ float bf2f(u16 b){ return __uint_as_float(((unsigned)b) << 16); }
__device__ __forceinline__ u16 f2h(float x){ __half h = __float2half(x); return *(u16*)&h; }
__device__ __forceinline__ float h2f(u16 b){ __half h; *(u16*)&h = b; return __half2float(h); }
// mish(x) = x*tanh(softplus(x)); tanh(log(1+e^x)) == (u^2-1)/(u^2+1), u = 1+e^x (exact identity)
// rcp approx (~2^-22) is absorbed by the bf16 round of every consumer
__device__ __forceinline__ float mishf(float x){
  float e = __expf(fminf(x, 30.f));
  float u = 1.f + e;
  float u2 = u * u;
  return x * (u2 - 1.f) * __builtin_amdgcn_rcpf(u2 + 1.f);
}

// ---------------- prep kernels ----------------
__global__ void prep_small(const float* __restrict__ deltas, const float* __restrict__ Wa,
                           const float* __restrict__ Wo, float* __restrict__ cps, float* __restrict__ wWo)
{
  const int t = threadIdx.x;
  if (t < NH){
    float cum[NC];
    float run = 0.f;
#pragma unroll
    for (int c = 0; c < NC; c++){
      float d = deltas[t*NC + c];
      float sp = (d > 20.f) ? d : log1pf(__expf(d));
      run += sp; cum[c] = run;
    }
    float s = 365.0f / run;
#pragma unroll
    for (int c = 0; c < NC; c++) cps[t*NC + c] = cum[c] * s;
  } else if (t >= 64 && t < 128){
    const int k = t - 64;
    float s = 0.f;
    for (int n = 0; n < HIDD; n++) s += Wa[k*HIDD + n] * Wo[n];
    wWo[k] = s;
  }
}

__global__ void prep_convert(const float* __restrict__ Wah, const float* __restrict__ Waa,
                             const float* __restrict__ Wb, const float* __restrict__ Wh,
                             u16* __restrict__ WahT, u16* __restrict__ WaaT,
                             u16* __restrict__ WbT, u16* __restrict__ WhT)
{
  int i = blockIdx.x * 256 + threadIdx.x;
  if (i < 262144){ int n = i >> 9, k = i & 511; WahT[i] = f2bf(Wah[k*512 + n]); return; }
  i -= 262144;
  if (i < 262144){ int n = i >> 9, k = i & 511; WaaT[i] = f2bf(Waa[k*512 + n]); return; }
  i -= 262144;
  if (i < 32768){ int n = i >> 6, k = i & 63; WbT[i] = f2bf(Wb[k*512 + n]); return; }
  i -= 32768;
  if (i < 16384){ int h = i >> 10, r = i & 1023, d = r >> 5, c = r & 31;
                  WhT[i] = f2bf(Wh[h*1024 + c*32 + d]); return; }
}

// ---------------- stage 1: 64 rows/block (4x16-row pipeline), hoisted weights, prefetched in_l ----------------
__global__ __launch_bounds__(256) void stage1_kernel(
    const float* __restrict__ inputs, const float* __restrict__ sku,
    const float* __restrict__ ln_g, const float* __restrict__ ln_b,
    const float* __restrict__ attnw, const float* __restrict__ cps,
    const float* __restrict__ wWo, const u16* __restrict__ WhT,
    u16* __restrict__ agg, u16* __restrict__ skub, float* __restrict__ skd)
{
  __shared__ __align__(16) float in_l[256];
  __shared__ __align__(16) float cps_l[512];
  __shared__ __align__(16) float gam_l[512];
  __shared__ __align__(16) float bet_l[512];
  __shared__ float aw_l[16];
  __shared__ __align__(16) u16 at_l[16*16*32];   // [h][b16][c32]
  __shared__ __align__(16) u16 ot_l[16*512];     // [b16][512]

  const int t = threadIdx.x;
  const int ln = t & 63;
  const long bb = (long)blockIdx.x * 64;          // 64 batch rows per block

  cps_l[t] = cps[t];       cps_l[t+256] = cps[t+256];
  gam_l[t] = ln_g[t];      gam_l[t+256] = ln_g[t+256];
  bet_l[t] = ln_b[t];      bet_l[t+256] = ln_b[t+256];
  if (t < 16) aw_l[t] = attnw[t];
  in_l[t] = inputs[bb*16 + t];                    // rows for sub-iter 0

  // sku -> bf16 + skd for all 64 rows (global-only, no LDS dependency)
#pragma unroll
  for (int it = 0; it < 4; it++){
    const long bs = bb + it*16;
    const f32x4 sv = *(const f32x4*)&sku[bs*64 + t*4];
    unsigned lo = (unsigned)f2bf(sv.x) | ((unsigned)f2bf(sv.y) << 16);
    unsigned hi = (unsigned)f2bf(sv.z) | ((unsigned)f2bf(sv.w) << 16);
    unsigned long long v = (unsigned long long)lo | ((unsigned long long)hi << 32);
    *(unsigned long long*)&skub[bs*64 + t*4] = v;
    const f32x4 wv4 = *(const f32x4*)&wWo[(ln & 15)*4];
    float pd = sv.x*wv4.x + sv.y*wv4.y + sv.z*wv4.z + sv.w*wv4.w;
#pragma unroll
    for (int s = 1; s < 16; s <<= 1) pd += __shfl_xor(pd, s);
    if ((ln & 15) == 0) skd[bs + (t >> 4)] = pd;
  }

  const int h = t >> 4, bi = t & 15;
  const int wv = t >> 6;
  const int lrow = ln & 15, lq = ln >> 4;

  // hoist WhT MFMA fragments (identical across sub-iterations): 8 x short8 = 32 VGPR
  short8 wf0[4], wf1[4];
#pragma unroll
  for (int q = 0; q < 4; q++){
    const int hh = wv*4 + q;
    wf0[q] = *(const short8*)&WhT[hh*1024 + lrow*32 + lq*8];
    wf1[q] = *(const short8*)&WhT[hh*1024 + (16 + lrow)*32 + lq*8];
  }
  __syncthreads();

#pragma unroll 1
  for (int it = 0; it < 4; it++){
    // ---- phase B: feats -> LN -> softmax -> attended (bf16) into at_l ----
    const float x = in_l[bi*16 + h];
    const float awv = aw_l[h] * (1.0f/0.7f);
    float nrm[NC];
    float s1 = 0.f;
#pragma unroll
    for (int c = 0; c < NC; c++){ float f = fmaxf(x - cps_l[h*NC + c], 0.f); nrm[c] = f; s1 += f; }
    const float mu = s1 * (1.f/NC);
    float s2 = 0.f;
#pragma unroll
    for (int c = 0; c < NC; c++){ float d = nrm[c] - mu; s2 += d*d; }
    const float rs = rsqrtf(s2 * (1.f/NC) + 1e-3f);
    float lmax = -1e30f;
#pragma unroll
    for (int c = 0; c < NC; c++){
      float nv = (nrm[c] - mu) * rs * gam_l[h*NC + c] + bet_l[h*NC + c];
      nrm[c] = nv;
      lmax = fmaxf(lmax, nv * awv);
    }
    float ps = 0.f;
#pragma unroll
    for (int c = 0; c < NC; c++) ps += __expf(nrm[c]*awv - lmax);
    const float invs = __builtin_amdgcn_rcpf(ps);
#pragma unroll
    for (int c = 0; c < NC; c += 2){
      const float p0 = __expf(nrm[c]*awv - lmax) * invs;
      const float p1 = __expf(nrm[c+1]*awv - lmax) * invs;
      unsigned pk = (unsigned)f2bf(nrm[c]*p0) | ((unsigned)f2bf(nrm[c+1]*p1) << 16);
      *(unsigned*)&at_l[h*512 + bi*32 + c] = pk;
    }
    __syncthreads();

    // prefetch next sub-iter's input rows (consumed only after 2 more barriers)
    if (it < 3) in_l[t] = inputs[(bb + (it+1)*16)*16 + t];

    // ---- phase C: einsum via MFMA (hoisted W fragments) -> mish -> ot_l ----
#pragma unroll
    for (int q = 0; q < 4; q++){
      const int hh = wv*4 + q;
      short8 af = *(const short8*)&at_l[hh*512 + lrow*32 + lq*8];
      f32x4 acc0 = {0.f,0.f,0.f,0.f}, acc1 = {0.f,0.f,0.f,0.f};
      acc0 = __builtin_amdgcn_mfma_f32_16x16x32_bf16(af, wf0[q], acc0, 0, 0, 0);
      acc1 = __builtin_amdgcn_mfma_f32_16x16x32_bf16(af, wf1[q], acc1, 0, 0, 0);
#pragma unroll
      for (int r = 0; r < 4; r++){
        const int br = lq*4 + r;
        ot_l[br*512 + hh*32 + lrow]      = f2bf(mishf(acc0[r]));
        ot_l[br*512 + hh*32 + 16 + lrow] = f2bf(mishf(acc1[r]));
      }
    }
    __syncthreads();

    // ---- phase D: coalesced copy ot_l -> agg ----
    {
      const int row = t >> 4, c16 = t & 15;
      const i32x4* src = (const i32x4*)&ot_l[row*512 + c16*32];
      i32x4* dst = (i32x4*)&agg[(bb + it*16 + row)*512 + c16*32];
#pragma unroll
      for (int j = 0; j < 4; j++) dst[j] = src[j];
    }
    __syncthreads();
  }
}

// ---------------- gemm1: 256x256 tile, K=512, 8-wave 4-phase deep pipeline (counted vmcnt) ----------------
// aggh = mish(agg @ WahT). LDS 128 KB: 2 kt-bufs x { A[2kh][256][32] | B[2kh][256][32] } bf16,
// group-XOR swizzled (proven pattern). Phases per kt: (kh0,mh0)(kh0,mh1)(kh1,mh0)(kh1,mh1);
// vmcnt(8) at ph0/ph2 keeps 4 half-tiles (8 loads) in flight across barriers.
#define PHASE(KH, MH) do { \
  const int buf_ = kt & 1; \
  const int abase_ = buf_*16384 + (KH)*8192; \
  const int bbase_ = 32768 + buf_*16384 + (KH)*8192; \
  short8 a_[4], b_[4]; \
  _Pragma("unroll") \
  for (int i = 0; i < 4; i++){ \
    const int row_ = wm*128 + (MH)*64 + i*16 + lrow; \
    a_[i] = *(const short8*)&smem[abase_ + row_*32 + (lq ^ ((row_ >> 1) & 3))*8]; \
    const int nrow_ = wn*64 + i*16 + lrow; \
    b_[i] = *(const short8*)&smem[bbase_ + nrow_*32 + (lq ^ ((nrow_ >> 1) & 3))*8]; \
  } \
  __builtin_amdgcn_s_setprio(1); \
  _Pragma("unroll") \
  for (int i = 0; i < 4; i++) \
    _Pragma("unroll") \
    for (int j = 0; j < 4; j++) \
      acc[(MH)*4 + i][j] = __builtin_amdgcn_mfma_f32_16x16x32_bf16(a_[i], b_[j], acc[(MH)*4 + i][j], 0, 0, 0); \
  __builtin_amdgcn_s_setprio(0); \
} while(0)

__global__ __launch_bounds__(512, 1) void gemm1(
    const u16* __restrict__ A, const u16* __restrict__ Bt, u16* __restrict__ aggh)
{
  __shared__ __align__(16) u16 smem[65536];   // 128 KB
  const int t = threadIdx.x, wid = t >> 6, ln = t & 63;
  const int lrow = ln & 15, lq = ln >> 4;
  const int wm = wid >> 2, wn = wid & 3;      // 2M x 4N waves; wave tile 128x64
  const int g = blockIdx.x;
  const long m0 = (long)(g >> 1) * 256;
  const int n0 = (g & 1) * 256;

  auto stageA = [&](int kt_, int kh_){
#pragma unroll
    for (int l = 0; l < 2; l++){
      const int slot = t + l*512;
      const int row = slot >> 2, kc = slot & 3;
      const int kcl = kc ^ ((row >> 1) & 3);
      GLLDS(&A[(m0 + row)*512 + kt_*64 + kh_*32 + kcl*8],
            &smem[(kt_ & 1)*16384 + kh_*8192 + slot*8]);
    }
  };
  auto stageB = [&](int kt_, int kh_){
#pragma unroll
    for (int l = 0; l < 2; l++){
      const int slot = t + l*512;
      const int row = slot >> 2, kc = slot & 3;
      const int kcl = kc ^ ((row >> 1) & 3);
      GLLDS(&Bt[(n0 + row)*512 + kt_*64 + kh_*32 + kcl*8],
            &smem[32768 + (kt_ & 1)*16384 + kh_*8192 + slot*8]);
    }
  };

  f32x4 acc[8][4] = {};
  // prologue: kt0 both K-halves + kt1 kh0 (6 half-tiles, 12 loads/thread in flight)
  stageA(0, 0); stageB(0, 0); stageA(0, 1); stageB(0, 1); stageA(1, 0); stageB(1, 0);

#pragma unroll 1
  for (int kt = 0; kt < 8; kt++){
    // ph0 (kh0, mh0): wait kh0(kt) landed (4 newer half-tiles = 8 loads allowed in flight)
    if (kt < 7) asm volatile("s_waitcnt vmcnt(8)" ::: "memory");
    else        asm volatile("s_waitcnt vmcnt(4)" ::: "memory");
    __builtin_amdgcn_s_barrier();
    if (kt + 1 < 8) stageA(kt + 1, 1);
    PHASE(0, 0);
    // ph1 (kh0, mh1)
    __builtin_amdgcn_s_barrier();
    if (kt + 1 < 8) stageB(kt + 1, 1);
    PHASE(0, 1);
    // ph2 (kh1, mh0): wait kh1(kt) landed
    if (kt < 7) asm volatile("s_waitcnt vmcnt(8)" ::: "memory");
    else        asm volatile("s_waitcnt vmcnt(0)" ::: "memory");
    __builtin_amdgcn_s_barrier();
    if (kt + 2 < 8) stageA(kt + 2, 0);
    PHASE(1, 0);
    // ph3 (kh1, mh1)
    __builtin_amdgcn_s_barrier();
    if (kt + 2 < 8) stageB(kt + 2, 0);
    PHASE(1, 1);
  }

  // ---- epilogue: mish -> LDS bounce (TP=264) per 128-row half -> coalesced dwordx4 stores ----
  __syncthreads();
  const int TP = 264;
#pragma unroll 1
  for (int h = 0; h < 2; h++){
    if (wm == h){
#pragma unroll
      for (int mh = 0; mh < 2; mh++)
#pragma unroll
        for (int i = 0; i < 4; i++)
#pragma unroll
          for (int j = 0; j < 4; j++)
#pragma unroll
            for (int r = 0; r < 4; r++){
              const int row = mh*64 + i*16 + lq*4 + r;
              smem[row*TP + wn*64 + j*16 + lrow] = f2bf(mishf(acc[mh*4 + i][j][r]));
            }
    }
    __syncthreads();
#pragma unroll
    for (int it = 0; it < 8; it++){
      const int idx = it*512 + t;
      const int row = idx >> 5, ch = idx & 31;
      const i32x4 v = *(const i32x4*)&smem[row*TP + ch*8];
      *(i32x4*)&aggh[(m0 + h*128 + row)*512 + n0 + ch*8] = v;
    }
    __syncthreads();
  }
}
#undef PHASE

// ---------------- mega2f: fused GEMM3(bw) + GEMM2(logits) + split-softmax partials ----------------
// epilogue reads aggh directly from global (r5-proven pattern: 16-lane-contiguous u16 loads
// hidden under exp/shuffle VALU work) -- no restage, no vmcnt(0) drain, one less barrier
__global__ __launch_bounds__(256, 3) void mega2f(
    const u16* __restrict__ A, const u16* __restrict__ Bt,
    const u16* __restrict__ skub, const u16* __restrict__ WbT,
    const float* __restrict__ Wo, float* __restrict__ part)
{
  __shared__ __align__(16) u16 smem[24576];   // 48 KB, multi-phase reuse
  const int t = threadIdx.x, wv = t >> 6, ln = t & 63;
  const int g = blockIdx.x;
  const int m_idx = (g & 7) + ((g >> 5) << 3);
  const int n_idx = (g >> 3) & 3;
  const long m0 = (long)m_idx * 128;
  const int n0 = n_idx * 128;
  const int lrow = ln & 15, lq = ln >> 4;
  const int wm = wv >> 1, wn = wv & 1;
  const float inv_t = 1.0f / 0.7f;

  // ---- phase 0: GEMM3 (K=64): bw = f2h(sigmoid(skub@WbT)*Wo) into regs ----
  u32 bwp[4][4][2];
  {
    auto stage3 = [&](int buf, int kt){
#pragma unroll
      for (int p = 0; p < 2; p++){
        const int chunk = p*256 + wv*64 + ln;
        const int mm = chunk >> 2, kc = chunk & 3;
        const int kcl = kc ^ ((mm >> 1) & 3);
        GLLDS(&skub[(m0 + mm)*64 + kt + kcl*8], &smem[buf*4096 + (p*256 + wv*64)*8]);
        GLLDS(&WbT[(n0 + mm)*64 + kt + kcl*8],  &smem[8192 + buf*4096 + (p*256 + wv*64)*8]);
      }
    };
    f32x4 acc3[4][4] = {};
    stage3(0, 0); stage3(1, 32);
    asm volatile("s_waitcnt vmcnt(0)" ::: "memory");
    __builtin_amdgcn_s_barrier();
#pragma unroll
    for (int ks3 = 0; ks3 < 2; ks3++){
      short8 a3[4], b3[4];
#pragma unroll
      for (int i = 0; i < 4; i++){
        const int ra = wm*64 + i*16 + lrow;
        const int rb = wn*64 + i*16 + lrow;
        const int lqa = lq ^ ((ra >> 1) & 3);
        const int lqb = lq ^ ((rb >> 1) & 3);
        a3[i] = *(const short8*)&smem[ks3*4096 + ra*32 + lqa*8];
        b3[i] = *(const short8*)&smem[8192 + ks3*4096 + rb*32 + lqb*8];
      }
#pragma unroll
      for (int i = 0; i < 4; i++)
#pragma unroll
        for (int j = 0; j < 4; j++)
          acc3[i][j] = __builtin_amdgcn_mfma_f32_16x16x32_bf16(a3[i], b3[j], acc3[i][j], 0, 0, 0);
    }
#pragma unroll
    for (int j = 0; j < 4; j++){
      const float wo = Wo[n0 + wn*64 + j*16 + lrow];
#pragma unroll
      for (int i = 0; i < 4; i++)
#pragma unroll
        for (int rp = 0; rp < 2; rp++){
          const float s0 = wo * __builtin_amdgcn_rcpf(1.f + __expf(-acc3[i][j][2*rp]));
          const float s1 = wo * __builtin_amdgcn_rcpf(1.f + __expf(-acc3[i][j][2*rp+1]));
          bwp[i][j][rp] = (u32)f2h(s0) | ((u32)f2h(s1) << 16);
        }
    }
  }
  __syncthreads();   // GEMM3 LDS reads complete before ring staging overwrites

  // ---- phase 1: GEMM2 K-loop (3-buffer ring) ----
  auto stage = [&](int buf, int kt){
#pragma unroll
    for (int p = 0; p < 2; p++){
      const int chunk = p*256 + wv*64 + ln;
      const int mm = chunk >> 2, kc = chunk & 3;
      const int kcl = kc ^ ((mm >> 1) & 3);
      GLLDS(&A[(m0 + mm)*512 + kt + kcl*8],  &smem[buf*4096 + (p*256 + wv*64)*8]);
      GLLDS(&Bt[(n0 + mm)*512 + kt + kcl*8], &smem[12288 + buf*4096 + (p*256 + wv*64)*8]);
    }
  };

  f32x4 acc[4][4] = {};
  stage(0, 0); stage(1, 32);
#pragma unroll 1
  for (int ks = 0; ks < 16; ks++){
    const int cur = ks % 3;
    if (ks < 15) asm volatile("s_waitcnt vmcnt(4)" ::: "memory");
    else         asm volatile("s_waitcnt vmcnt(0)" ::: "memory");
    __builtin_amdgcn_s_barrier();
    if (ks + 2 < 16) stage((ks + 2) % 3, (ks + 2)*32);
    short8 a[4], b[4];
#pragma unroll
    for (int i = 0; i < 4; i++){
      const int ra = wm*64 + i*16 + lrow;
      const int rb = wn*64 + i*16 + lrow;
      const int lqa = lq ^ ((ra >> 1) & 3);
      const int lqb = lq ^ ((rb >> 1) & 3);
      a[i] = *(const short8*)&smem[cur*4096 + ra*32 + lqa*8];
      b[i] = *(const short8*)&smem[12288 + cur*4096 + rb*32 + lqb*8];
    }
#pragma unroll
    for (int i = 0; i < 4; i++)
#pragma unroll
      for (int j = 0; j < 4; j++)
        acc[i][j] = __builtin_amdgcn_mfma_f32_16x16x32_bf16(a[i], b[j], acc[i][j], 0, 0, 0);
  }

  // ---- phase 2: per-n-tile softmax partials; aggh direct from global, bw from bwp regs ----
  __syncthreads();
  float* mloc = (float*)smem;        // [128][2] stats overlay (K-loop LDS dead)
  float* sloc = mloc + 256;          // [128][2]
  float* tloc = sloc + 256;          // [128][2]

#pragma unroll
  for (int i = 0; i < 4; i++){
#pragma unroll
    for (int r = 0; r < 4; r++){
      float tm = acc[i][0][r];
#pragma unroll
      for (int j = 1; j < 4; j++) tm = fmaxf(tm, acc[i][j][r]);
#pragma unroll
      for (int s = 1; s < 16; s <<= 1) tm = fmaxf(tm, __shfl_xor(tm, s));
      const int rowL = wm*64 + i*16 + lq*4 + r;
      float sp = 0.f, tp = 0.f;
#pragma unroll
      for (int j = 0; j < 4; j++){
        const long gi = (m0 + rowL)*512 + n0 + wn*64 + j*16 + lrow;
        const float e = __expf((acc[i][j][r] - tm) * inv_t);
        const u16 bh = (u16)(bwp[i][j][r >> 1] >> ((r & 1)*16));
        sp += e; tp += e * bf2f(A[gi]) * h2f(bh);
      }
#pragma unroll
      for (int s = 1; s < 16; s <<= 1){ sp += __shfl_xor(sp, s); tp += __shfl_xor(tp, s); }
      if (lrow == 0){
        mloc[rowL*2 + wn] = tm; sloc[rowL*2 + wn] = sp; tloc[rowL*2 + wn] = tp;
      }
    }
  }
  __syncthreads();
  if (t < 128){
    const float ma = mloc[t*2], mb = mloc[t*2 + 1];
    const float M = fmaxf(ma, mb);
    const float wa = __expf((ma - M) * inv_t), wb = __expf((mb - M) * inv_t);
    const float S = sloc[t*2]*wa + sloc[t*2 + 1]*wb;
    const float T = tloc[t*2]*wa + tloc[t*2 + 1]*wb;
    float* pm = part + (size_t)n_idx*3*CHUNK;
    pm[m0 + t]           = M;
    pm[CHUNK + m0 + t]   = S;
    pm[2*CHUNK + m0 + t] = T;
  }
}

// ---------------- combine: merge 4 n-tile partials -> out = T/S + skd ----------------
__global__ __launch_bounds__(256) void combine_kernel(
    const float* __restrict__ part, const float* __restrict__ skd, float* __restrict__ outp)
{
  const int row = blockIdx.x*256 + threadIdx.x;
  const float inv_t = 1.0f / 0.7f;
  float M = -1e30f;
#pragma unroll
  for (int nt = 0; nt < 4; nt++) M = fmaxf(M, part[(size_t)nt*3*CHUNK + row]);
  float S = 0.f, T = 0.f;
#pragma unroll
  for (int nt = 0; nt < 4; nt++){
    const float w = __expf((part[(size_t)nt*3*CHUNK + row] - M) * inv_t);
    S += part[(size_t)nt*3*CHUNK + CHUNK + row] * w;
    T += part[(size_t)nt*3*CHUNK + 2*CHUNK + row] * w;
  }
  outp[row] = T / S + skd[row];
}

__global__ void ws_too_small(float* o, float v){ o[(long)blockIdx.x*256 + threadIdx.x] = v; }

extern "C" void kernel_launch(void* const* d_in, const int* in_sizes, int n_in,
                              void* d_out, int out_size, void* d_ws, size_t ws_size,
                              hipStream_t stream)
{
  const float* inputs = (const float*)d_in[0];
  const float* sku    = (const float*)d_in[1];
  const float* deltas = (const float*)d_in[2];
  const float* ln_g   = (const float*)d_in[3];
  const float* ln_b   = (const float*)d_in[4];
  const float* attnw  = (const float*)d_in[5];
  const float* Wh     = (const float*)d_in[6];
  const float* Wah    = (const float*)d_in[7];
  const float* Waa    = (const float*)d_in[8];
  const float* Wb     = (const float*)d_in[9];
  const float* Wa     = (const float*)d_in[10];
  const float* Wo     = (const float*)d_in[11];
  float* outp = (float*)d_out;

  const size_t OFF_CPS  = 0;
  const size_t OFF_WWO  = 2048;
  const size_t OFF_WAHT = 4096;
  const size_t OFF_WAAT = OFF_WAHT + 524288;
  const size_t OFF_WBT  = OFF_WAAT + 524288;
  const size_t OFF_WHT  = OFF_WBT  + 65536;
  const size_t OFF_SKUB = OFF_WHT  + 32768;
  const size_t OFF_SKD  = OFF_SKUB + (size_t)CHUNK*64*2;
  const size_t OFF_AGG  = OFF_SKD  + (size_t)CHUNK*4;
  const size_t OFF_AGH  = OFF_AGG  + (size_t)CHUNK*512*2;
  const size_t OFF_PART = OFF_AGH  + (size_t)CHUNK*512*2;
  const size_t NEED     = OFF_PART + (size_t)4*3*CHUNK*4;   // ~140 MB

  if (ws_size < NEED){
    hipLaunchKernelGGL(ws_too_small, dim3(B_TOT/256), dim3(256), 0, stream,
                       outp, -(float)(ws_size >> 20));
    return;
  }

  char* ws = (char*)d_ws;
  float* cps  = (float*)(ws + OFF_CPS);
  float* wWo  = (float*)(ws + OFF_WWO);
  u16* WahT   = (u16*)(ws + OFF_WAHT);
  u16* WaaT   = (u16*)(ws + OFF_WAAT);
  u16* WbT    = (u16*)(ws + OFF_WBT);
  u16* WhT    = (u16*)(ws + OFF_WHT);
  u16* skub   = (u16*)(ws + OFF_SKUB);
  float* skd  = (float*)(ws + OFF_SKD);
  u16* agg    = (u16*)(ws + OFF_AGG);
  u16* aggh   = (u16*)(ws + OFF_AGH);
  float* part = (float*)(ws + OFF_PART);

  hipLaunchKernelGGL(prep_small, dim3(1), dim3(128), 0, stream, deltas, Wa, Wo, cps, wWo);
  hipLaunchKernelGGL(prep_convert, dim3(2240), dim3(256), 0, stream,
                     Wah, Waa, Wb, Wh, WahT, WaaT, WbT, WhT);

  for (int ch = 0; ch < B_TOT / CHUNK; ch++){
    const float* in_c  = inputs + (size_t)ch * CHUNK * 16;
    const float* sku_c = sku    + (size_t)ch * CHUNK * 64;
    float* out_c       = outp   + (size_t)ch * CHUNK;

    hipLaunchKernelGGL(stage1_kernel, dim3(CHUNK/64), dim3(256), 0, stream,
                       in_c, sku_c, ln_g, ln_b, attnw, cps, wWo, WhT, agg, skub, skd);
    hipLaunchKernelGGL(gemm1, dim3(CHUNK/256*2), dim3(512), 0, stream,
                       agg, WahT, aggh);
    hipLaunchKernelGGL(mega2f, dim3(CHUNK/128*4), dim3(256), 0, stream,
                       aggh, WaaT, skub, WbT, Wo, part);
    hipLaunchKernelGGL(combine_kernel, dim3(CHUNK/256), dim3(256), 0, stream,
                       part, skd, out_c);
  }
}

// Round 12
// 450.384 us; speedup vs baseline: 1.0344x; 1.0344x over previous
//
#include <hip/hip_runtime.h>
#include <hip/hip_fp16.h>
#include <stdint.h>

#define B_TOT 131072
#define CHUNK 65536
#define NH 16
#define NC 32
#define HIDD 512

typedef unsigned short u16;
typedef unsigned int u32;
typedef __attribute__((ext_vector_type(8))) short short8;
typedef __attribute__((ext_vector_type(4))) float f32x4;
typedef __attribute__((ext_vector_type(4))) int i32x4;

#define GLLDS(g, l) __builtin_amdgcn_global_load_lds((const __attribute__((address_space(1))) unsigned int*)(g), (__attribute__((address_space(3))) unsigned int*)(l), 16, 0, 0)

__device__ __forceinline__ u16 f2bf(float x){
  unsigned u = __float_as_uint(x);
  u += 0x7fffu + ((u >> 16) & 1u);
  return (u16)(u >> 16);
}
__device__ __forceinline__ float bf2f(u16 b){ return __uint_as_float(((unsigned)b) << 16); }
__device__ __forceinline__ u16 f2h(float x){ __half h = __float2half(x); return *(u16*)&h; }
__device__ __forceinline__ float h2f(u16 b){ __half h; *(u16*)&h = b; return __half2float(h); }
// mish(x) = x*tanh(softplus(x)); tanh(log(1+e^x)) == (u^2-1)/(u^2+1), u = 1+e^x (exact identity)
// rcp approx (~2^-22) is absorbed by the bf16 round of every consumer
__device__ __forceinline__ float mishf(float x){
  float e = __expf(fminf(x, 30.f));
  float u = 1.f + e;
  float u2 = u * u;
  return x * (u2 - 1.f) * __builtin_amdgcn_rcpf(u2 + 1.f);
}

// ---------------- prep kernels ----------------
__global__ void prep_small(const float* __restrict__ deltas, const float* __restrict__ Wa,
                           const float* __restrict__ Wo, float* __restrict__ cps, float* __restrict__ wWo)
{
  const int t = threadIdx.x;
  if (t < NH){
    float cum[NC];
    float run = 0.f;
#pragma unroll
    for (int c = 0; c < NC; c++){
      float d = deltas[t*NC + c];
      float sp = (d > 20.f) ? d : log1pf(__expf(d));
      run += sp; cum[c] = run;
    }
    float s = 365.0f / run;
#pragma unroll
    for (int c = 0; c < NC; c++) cps[t*NC + c] = cum[c] * s;
  } else if (t >= 64 && t < 128){
    const int k = t - 64;
    float s = 0.f;
    for (int n = 0; n < HIDD; n++) s += Wa[k*HIDD + n] * Wo[n];
    wWo[k] = s;
  }
}

__global__ void prep_convert(const float* __restrict__ Wah, const float* __restrict__ Waa,
                             const float* __restrict__ Wb, const float* __restrict__ Wh,
                             u16* __restrict__ WahT, u16* __restrict__ WaaT,
                             u16* __restrict__ WbT, u16* __restrict__ WhT)
{
  int i = blockIdx.x * 256 + threadIdx.x;
  if (i < 262144){ int n = i >> 9, k = i & 511; WahT[i] = f2bf(Wah[k*512 + n]); return; }
  i -= 262144;
  if (i < 262144){ int n = i >> 9, k = i & 511; WaaT[i] = f2bf(Waa[k*512 + n]); return; }
  i -= 262144;
  if (i < 32768){ int n = i >> 6, k = i & 63; WbT[i] = f2bf(Wb[k*512 + n]); return; }
  i -= 32768;
  if (i < 16384){ int h = i >> 10, r = i & 1023, d = r >> 5, c = r & 31;
                  WhT[i] = f2bf(Wh[h*1024 + c*32 + d]); return; }
}

// ---------------- stage 1: 64 rows/block, BARRIER-FREE wave-local pipeline ----------------
// at_l[h] and ot_l cols [wv*128,+128) are produced and consumed by the SAME wave;
// per-wave LDS ordering makes the loop barrier-free. x is loaded per-lane from global.
__global__ __launch_bounds__(256) void stage1_kernel(
    const float* __restrict__ inputs, const float* __restrict__ sku,
    const float* __restrict__ ln_g, const float* __restrict__ ln_b,
    const float* __restrict__ attnw, const float* __restrict__ cps,
    const float* __restrict__ wWo, const u16* __restrict__ WhT,
    u16* __restrict__ agg, u16* __restrict__ skub, float* __restrict__ skd)
{
  __shared__ __align__(16) float cps_l[512];
  __shared__ __align__(16) float gam_l[512];
  __shared__ __align__(16) float bet_l[512];
  __shared__ float aw_l[16];
  __shared__ __align__(16) u16 at_l[16*16*32];   // [h][b16][c32]  (wave-local partitions)
  __shared__ __align__(16) u16 ot_l[16*512];     // [b16][512]     (wave-local col slices)

  const int t = threadIdx.x;
  const int ln = t & 63;
  const long bb = (long)blockIdx.x * 64;          // 64 batch rows per block

  cps_l[t] = cps[t];       cps_l[t+256] = cps[t+256];
  gam_l[t] = ln_g[t];      gam_l[t+256] = ln_g[t+256];
  bet_l[t] = ln_b[t];      bet_l[t+256] = ln_b[t+256];
  if (t < 16) aw_l[t] = attnw[t];

  // sku -> bf16 + skd for all 64 rows (global-only, no LDS dependency)
#pragma unroll
  for (int it = 0; it < 4; it++){
    const long bs = bb + it*16;
    const f32x4 sv = *(const f32x4*)&sku[bs*64 + t*4];
    unsigned lo = (unsigned)f2bf(sv.x) | ((unsigned)f2bf(sv.y) << 16);
    unsigned hi = (unsigned)f2bf(sv.z) | ((unsigned)f2bf(sv.w) << 16);
    unsigned long long v = (unsigned long long)lo | ((unsigned long long)hi << 32);
    *(unsigned long long*)&skub[bs*64 + t*4] = v;
    const f32x4 wv4 = *(const f32x4*)&wWo[(ln & 15)*4];
    float pd = sv.x*wv4.x + sv.y*wv4.y + sv.z*wv4.z + sv.w*wv4.w;
#pragma unroll
    for (int s = 1; s < 16; s <<= 1) pd += __shfl_xor(pd, s);
    if ((ln & 15) == 0) skd[bs + (t >> 4)] = pd;
  }

  const int wv = t >> 6;
  const int lrow = ln & 15, lq = ln >> 4;
  const int h = wv*4 + (ln >> 4);                 // == t>>4
  const int bi = ln & 15;                         // == t&15

  // hoist WhT MFMA fragments (identical across sub-iterations): 8 x short8 = 32 VGPR
  short8 wf0[4], wf1[4];
#pragma unroll
  for (int q = 0; q < 4; q++){
    const int hh = wv*4 + q;
    wf0[q] = *(const short8*)&WhT[hh*1024 + lrow*32 + lq*8];
    wf1[q] = *(const short8*)&WhT[hh*1024 + (16 + lrow)*32 + lq*8];
  }
  __syncthreads();   // read-only tables (cps/gam/bet/aw) visible; the ONLY barrier

  const float awv = aw_l[h] * (1.0f/0.7f);

#pragma unroll 1
  for (int it = 0; it < 4; it++){
    // ---- phase B: per-lane x load -> LN -> softmax -> attended (bf16) into wave-local at_l ----
    const float x = inputs[(bb + it*16 + bi)*16 + h];
    float nrm[NC];
    float s1 = 0.f;
#pragma unroll
    for (int c = 0; c < NC; c++){ float f = fmaxf(x - cps_l[h*NC + c], 0.f); nrm[c] = f; s1 += f; }
    const float mu = s1 * (1.f/NC);
    float s2 = 0.f;
#pragma unroll
    for (int c = 0; c < NC; c++){ float d = nrm[c] - mu; s2 += d*d; }
    const float rs = rsqrtf(s2 * (1.f/NC) + 1e-3f);
    float lmax = -1e30f;
#pragma unroll
    for (int c = 0; c < NC; c++){
      float nv = (nrm[c] - mu) * rs * gam_l[h*NC + c] + bet_l[h*NC + c];
      nrm[c] = nv;
      lmax = fmaxf(lmax, nv * awv);
    }
    float ps = 0.f;
#pragma unroll
    for (int c = 0; c < NC; c++) ps += __expf(nrm[c]*awv - lmax);
    const float invs = __builtin_amdgcn_rcpf(ps);
#pragma unroll
    for (int c = 0; c < NC; c += 2){
      const float p0 = __expf(nrm[c]*awv - lmax) * invs;
      const float p1 = __expf(nrm[c+1]*awv - lmax) * invs;
      unsigned pk = (unsigned)f2bf(nrm[c]*p0) | ((unsigned)f2bf(nrm[c+1]*p1) << 16);
      *(unsigned*)&at_l[h*512 + bi*32 + c] = pk;
    }
    // no barrier: at_l[h] region is written and read by this wave only (per-wave DS ordering)

    // ---- phase C: einsum via MFMA (hoisted W fragments) -> mish -> wave-local ot_l cols ----
#pragma unroll
    for (int q = 0; q < 4; q++){
      const int hh = wv*4 + q;
      short8 af = *(const short8*)&at_l[hh*512 + lrow*32 + lq*8];
      f32x4 acc0 = {0.f,0.f,0.f,0.f}, acc1 = {0.f,0.f,0.f,0.f};
      acc0 = __builtin_amdgcn_mfma_f32_16x16x32_bf16(af, wf0[q], acc0, 0, 0, 0);
      acc1 = __builtin_amdgcn_mfma_f32_16x16x32_bf16(af, wf1[q], acc1, 0, 0, 0);
#pragma unroll
      for (int r = 0; r < 4; r++){
        const int br = lq*4 + r;
        ot_l[br*512 + hh*32 + lrow]      = f2bf(mishf(acc0[r]));
        ot_l[br*512 + hh*32 + 16 + lrow] = f2bf(mishf(acc1[r]));
      }
    }
    // no barrier: ot_l cols [wv*128, wv*128+128) written and read by this wave only

    // ---- phase D: wave-local coalesced copy of own col-slice -> agg ----
    {
      const int drow = ln >> 2, dsub = ln & 3;
      const i32x4* src = (const i32x4*)&ot_l[drow*512 + wv*128 + dsub*32];
      i32x4* dst = (i32x4*)&agg[(bb + it*16 + drow)*512 + wv*128 + dsub*32];
#pragma unroll
      for (int j = 0; j < 4; j++) dst[j] = src[j];
    }
    // no barrier: next iteration's at_l/ot_l writes are same-wave ordered after these reads
  }
}

// ---------------- gemm1: 128x128 tile, K=512, 3-buffer ring (48KB), depth-2 counted vmcnt ----------------
__global__ __launch_bounds__(256, 3) void gemm1(
    const u16* __restrict__ A, const u16* __restrict__ Bt, u16* __restrict__ aggh)
{
  __shared__ __align__(16) u16 smem[24576];   // As[3][4096] | Bs[3][4096] = 48 KB; bounce overlay after
  const int t = threadIdx.x, wv = t >> 6, ln = t & 63;
  const int g = blockIdx.x;
  const int m_idx = (g & 7) + ((g >> 5) << 3);
  const int n_idx = (g >> 3) & 3;
  const long m0 = (long)m_idx * 128;
  const int n0 = n_idx * 128;
  const int lrow = ln & 15, lq = ln >> 4;
  const int wm = wv >> 1, wn = wv & 1;

  auto stage = [&](int buf, int kt){
#pragma unroll
    for (int p = 0; p < 2; p++){
      const int chunk = p*256 + wv*64 + ln;
      const int mm = chunk >> 2, kc = chunk & 3;
      const int kcl = kc ^ ((mm >> 1) & 3);
      GLLDS(&A[(m0 + mm)*512 + kt + kcl*8],  &smem[buf*4096 + (p*256 + wv*64)*8]);
      GLLDS(&Bt[(n0 + mm)*512 + kt + kcl*8], &smem[12288 + buf*4096 + (p*256 + wv*64)*8]);
    }
  };

  f32x4 acc[4][4] = {};
  stage(0, 0); stage(1, 32);               // 8 GLLDS in flight (4 per stage)
#pragma unroll 1
  for (int ks = 0; ks < 16; ks++){
    const int cur = ks % 3;
    // counted vmcnt: oldest stage (buf cur, 4 loads) must be done; newest stays in flight
    if (ks < 15) asm volatile("s_waitcnt vmcnt(4)" ::: "memory");
    else         asm volatile("s_waitcnt vmcnt(0)" ::: "memory");
    __builtin_amdgcn_s_barrier();
    if (ks + 2 < 16) stage((ks + 2) % 3, (ks + 2)*32);
    short8 a[4], b[4];
#pragma unroll
    for (int i = 0; i < 4; i++){
      const int ra = wm*64 + i*16 + lrow;
      const int rb = wn*64 + i*16 + lrow;
      const int lqa = lq ^ ((ra >> 1) & 3);
      const int lqb = lq ^ ((rb >> 1) & 3);
      a[i] = *(const short8*)&smem[cur*4096 + ra*32 + lqa*8];
      b[i] = *(const short8*)&smem[12288 + cur*4096 + rb*32 + lqb*8];
    }
#pragma unroll
    for (int i = 0; i < 4; i++)
#pragma unroll
      for (int j = 0; j < 4; j++)
        acc[i][j] = __builtin_amdgcn_mfma_f32_16x16x32_bf16(a[i], b[j], acc[i][j], 0, 0, 0);
  }

  // coalesced epilogue: bounce each 64-row half through LDS, stream out dwordx4
  const int TP = 136;   // 64*136 u16 = 17408 B
  __syncthreads();
#pragma unroll 1
  for (int h = 0; h < 2; h++){
    if (wm == h){
#pragma unroll
      for (int i = 0; i < 4; i++)
#pragma unroll
        for (int j = 0; j < 4; j++)
#pragma unroll
          for (int r = 0; r < 4; r++)
            smem[(i*16 + lq*4 + r)*TP + wn*64 + j*16 + lrow] = f2bf(mishf(acc[i][j][r]));
    }
    __syncthreads();
#pragma unroll
    for (int it = 0; it < 4; it++){
      const int idx = it*256 + t;
      const int row = idx >> 4, ch = idx & 15;
      const i32x4 v = *(const i32x4*)&smem[row*TP + ch*8];
      *(i32x4*)&aggh[(m0 + h*64 + row)*512 + n0 + ch*8] = v;
    }
    __syncthreads();
  }
}

// ---------------- mega2f: fused GEMM3(bw) + GEMM2(logits) + split-softmax partials ----------------
// epilogue reads aggh directly from global (r5-proven pattern: 16-lane-contiguous u16 loads
// hidden under exp/shuffle VALU work) -- no restage, no vmcnt(0) drain, one less barrier
__global__ __launch_bounds__(256, 3) void mega2f(
    const u16* __restrict__ A, const u16* __restrict__ Bt,
    const u16* __restrict__ skub, const u16* __restrict__ WbT,
    const float* __restrict__ Wo, float* __restrict__ part)
{
  __shared__ __align__(16) u16 smem[24576];   // 48 KB, multi-phase reuse
  const int t = threadIdx.x, wv = t >> 6, ln = t & 63;
  const int g = blockIdx.x;
  const int m_idx = (g & 7) + ((g >> 5) << 3);
  const int n_idx = (g >> 3) & 3;
  const long m0 = (long)m_idx * 128;
  const int n0 = n_idx * 128;
  const int lrow = ln & 15, lq = ln >> 4;
  const int wm = wv >> 1, wn = wv & 1;
  const float inv_t = 1.0f / 0.7f;

  // ---- phase 0: GEMM3 (K=64): bw = f2h(sigmoid(skub@WbT)*Wo) into regs ----
  u32 bwp[4][4][2];
  {
    auto stage3 = [&](int buf, int kt){
#pragma unroll
      for (int p = 0; p < 2; p++){
        const int chunk = p*256 + wv*64 + ln;
        const int mm = chunk >> 2, kc = chunk & 3;
        const int kcl = kc ^ ((mm >> 1) & 3);
        GLLDS(&skub[(m0 + mm)*64 + kt + kcl*8], &smem[buf*4096 + (p*256 + wv*64)*8]);
        GLLDS(&WbT[(n0 + mm)*64 + kt + kcl*8],  &smem[8192 + buf*4096 + (p*256 + wv*64)*8]);
      }
    };
    f32x4 acc3[4][4] = {};
    stage3(0, 0); stage3(1, 32);
    asm volatile("s_waitcnt vmcnt(0)" ::: "memory");
    __builtin_amdgcn_s_barrier();
#pragma unroll
    for (int ks3 = 0; ks3 < 2; ks3++){
      short8 a3[4], b3[4];
#pragma unroll
      for (int i = 0; i < 4; i++){
        const int ra = wm*64 + i*16 + lrow;
        const int rb = wn*64 + i*16 + lrow;
        const int lqa = lq ^ ((ra >> 1) & 3);
        const int lqb = lq ^ ((rb >> 1) & 3);
        a3[i] = *(const short8*)&smem[ks3*4096 + ra*32 + lqa*8];
        b3[i] = *(const short8*)&smem[8192 + ks3*4096 + rb*32 + lqb*8];
      }
#pragma unroll
      for (int i = 0; i < 4; i++)
#pragma unroll
        for (int j = 0; j < 4; j++)
          acc3[i][j] = __builtin_amdgcn_mfma_f32_16x16x32_bf16(a3[i], b3[j], acc3[i][j], 0, 0, 0);
    }
#pragma unroll
    for (int j = 0; j < 4; j++){
      const float wo = Wo[n0 + wn*64 + j*16 + lrow];
#pragma unroll
      for (int i = 0; i < 4; i++)
#pragma unroll
        for (int rp = 0; rp < 2; rp++){
          const float s0 = wo * __builtin_amdgcn_rcpf(1.f + __expf(-acc3[i][j][2*rp]));
          const float s1 = wo * __builtin_amdgcn_rcpf(1.f + __expf(-acc3[i][j][2*rp+1]));
          bwp[i][j][rp] = (u32)f2h(s0) | ((u32)f2h(s1) << 16);
        }
    }
  }
  __syncthreads();   // GEMM3 LDS reads complete before ring staging overwrites

  // ---- phase 1: GEMM2 K-loop (3-buffer ring) ----
  auto stage = [&](int buf, int kt){
#pragma unroll
    for (int p = 0; p < 2; p++){
      const int chunk = p*256 + wv*64 + ln;
      const int mm = chunk >> 2, kc = chunk & 3;
      const int kcl = kc ^ ((mm >> 1) & 3);
      GLLDS(&A[(m0 + mm)*512 + kt + kcl*8],  &smem[buf*4096 + (p*256 + wv*64)*8]);
      GLLDS(&Bt[(n0 + mm)*512 + kt + kcl*8], &smem[12288 + buf*4096 + (p*256 + wv*64)*8]);
    }
  };

  f32x4 acc[4][4] = {};
  stage(0, 0); stage(1, 32);
#pragma unroll 1
  for (int ks = 0; ks < 16; ks++){
    const int cur = ks % 3;
    if (ks < 15) asm volatile("s_waitcnt vmcnt(4)" ::: "memory");
    else         asm volatile("s_waitcnt vmcnt(0)" ::: "memory");
    __builtin_amdgcn_s_barrier();
    if (ks + 2 < 16) stage((ks + 2) % 3, (ks + 2)*32);
    short8 a[4], b[4];
#pragma unroll
    for (int i = 0; i < 4; i++){
      const int ra = wm*64 + i*16 + lrow;
      const int rb = wn*64 + i*16 + lrow;
      const int lqa = lq ^ ((ra >> 1) & 3);
      const int lqb = lq ^ ((rb >> 1) & 3);
      a[i] = *(const short8*)&smem[cur*4096 + ra*32 + lqa*8];
      b[i] = *(const short8*)&smem[12288 + cur*4096 + rb*32 + lqb*8];
    }
#pragma unroll
    for (int i = 0; i < 4; i++)
#pragma unroll
      for (int j = 0; j < 4; j++)
        acc[i][j] = __builtin_amdgcn_mfma_f32_16x16x32_bf16(a[i], b[j], acc[i][j], 0, 0, 0);
  }

  // ---- phase 2: per-n-tile softmax partials; aggh direct from global, bw from bwp regs ----
  __syncthreads();
  float* mloc = (float*)smem;        // [128][2] stats overlay (K-loop LDS dead)
  float* sloc = mloc + 256;          // [128][2]
  float* tloc = sloc + 256;          // [128][2]

#pragma unroll
  for (int i = 0; i < 4; i++){
#pragma unroll
    for (int r = 0; r < 4; r++){
      float tm = acc[i][0][r];
#pragma unroll
      for (int j = 1; j < 4; j++) tm = fmaxf(tm, acc[i][j][r]);
#pragma unroll
      for (int s = 1; s < 16; s <<= 1) tm = fmaxf(tm, __shfl_xor(tm, s));
      const int rowL = wm*64 + i*16 + lq*4 + r;
      float sp = 0.f, tp = 0.f;
#pragma unroll
      for (int j = 0; j < 4; j++){
        const long gi = (m0 + rowL)*512 + n0 + wn*64 + j*16 + lrow;
        const float e = __expf((acc[i][j][r] - tm) * inv_t);
        const u16 bh = (u16)(bwp[i][j][r >> 1] >> ((r & 1)*16));
        sp += e; tp += e * bf2f(A[gi]) * h2f(bh);
      }
#pragma unroll
      for (int s = 1; s < 16; s <<= 1){ sp += __shfl_xor(sp, s); tp += __shfl_xor(tp, s); }
      if (lrow == 0){
        mloc[rowL*2 + wn] = tm; sloc[rowL*2 + wn] = sp; tloc[rowL*2 + wn] = tp;
      }
    }
  }
  __syncthreads();
  if (t < 128){
    const float ma = mloc[t*2], mb = mloc[t*2 + 1];
    const float M = fmaxf(ma, mb);
    const float wa = __expf((ma - M) * inv_t), wb = __expf((mb - M) * inv_t);
    const float S = sloc[t*2]*wa + sloc[t*2 + 1]*wb;
    const float T = tloc[t*2]*wa + tloc[t*2 + 1]*wb;
    float* pm = part + (size_t)n_idx*3*CHUNK;
    pm[m0 + t]           = M;
    pm[CHUNK + m0 + t]   = S;
    pm[2*CHUNK + m0 + t] = T;
  }
}

// ---------------- combine: merge 4 n-tile partials -> out = T/S + skd ----------------
__global__ __launch_bounds__(256) void combine_kernel(
    const float* __restrict__ part, const float* __restrict__ skd, float* __restrict__ outp)
{
  const int row = blockIdx.x*256 + threadIdx.x;
  const float inv_t = 1.0f / 0.7f;
  float M = -1e30f;
#pragma unroll
  for (int nt = 0; nt < 4; nt++) M = fmaxf(M, part[(size_t)nt*3*CHUNK + row]);
  float S = 0.f, T = 0.f;
#pragma unroll
  for (int nt = 0; nt < 4; nt++){
    const float w = __expf((part[(size_t)nt*3*CHUNK + row] - M) * inv_t);
    S += part[(size_t)nt*3*CHUNK + CHUNK + row] * w;
    T += part[(size_t)nt*3*CHUNK + 2*CHUNK + row] * w;
  }
  outp[row] = T / S + skd[row];
}

__global__ void ws_too_small(float* o, float v){ o[(long)blockIdx.x*256 + threadIdx.x] = v; }

extern "C" void kernel_launch(void* const* d_in, const int* in_sizes, int n_in,
                              void* d_out, int out_size, void* d_ws, size_t ws_size,
                              hipStream_t stream)
{
  const float* inputs = (const float*)d_in[0];
  const float* sku    = (const float*)d_in[1];
  const float* deltas = (const float*)d_in[2];
  const float* ln_g   = (const float*)d_in[3];
  const float* ln_b   = (const float*)d_in[4];
  const float* attnw  = (const float*)d_in[5];
  const float* Wh     = (const float*)d_in[6];
  const float* Wah    = (const float*)d_in[7];
  const float* Waa    = (const float*)d_in[8];
  const float* Wb     = (const float*)d_in[9];
  const float* Wa     = (const float*)d_in[10];
  const float* Wo     = (const float*)d_in[11];
  float* outp = (float*)d_out;

  const size_t OFF_CPS  = 0;
  const size_t OFF_WWO  = 2048;
  const size_t OFF_WAHT = 4096;
  const size_t OFF_WAAT = OFF_WAHT + 524288;
  const size_t OFF_WBT  = OFF_WAAT + 524288;
  const size_t OFF_WHT  = OFF_WBT  + 65536;
  const size_t OFF_SKUB = OFF_WHT  + 32768;
  const size_t OFF_SKD  = OFF_SKUB + (size_t)CHUNK*64*2;
  const size_t OFF_AGG  = OFF_SKD  + (size_t)CHUNK*4;
  const size_t OFF_AGH  = OFF_AGG  + (size_t)CHUNK*512*2;
  const size_t OFF_PART = OFF_AGH  + (size_t)CHUNK*512*2;
  const size_t NEED     = OFF_PART + (size_t)4*3*CHUNK*4;   // ~140 MB

  if (ws_size < NEED){
    hipLaunchKernelGGL(ws_too_small, dim3(B_TOT/256), dim3(256), 0, stream,
                       outp, -(float)(ws_size >> 20));
    return;
  }

  char* ws = (char*)d_ws;
  float* cps  = (float*)(ws + OFF_CPS);
  float* wWo  = (float*)(ws + OFF_WWO);
  u16* WahT   = (u16*)(ws + OFF_WAHT);
  u16* WaaT   = (u16*)(ws + OFF_WAAT);
  u16* WbT    = (u16*)(ws + OFF_WBT);
  u16* WhT    = (u16*)(ws + OFF_WHT);
  u16* skub   = (u16*)(ws + OFF_SKUB);
  float* skd  = (float*)(ws + OFF_SKD);
  u16* agg    = (u16*)(ws + OFF_AGG);
  u16* aggh   = (u16*)(ws + OFF_AGH);
  float* part = (float*)(ws + OFF_PART);

  hipLaunchKernelGGL(prep_small, dim3(1), dim3(128), 0, stream, deltas, Wa, Wo, cps, wWo);
  hipLaunchKernelGGL(prep_convert, dim3(2240), dim3(256), 0, stream,
                     Wah, Waa, Wb, Wh, WahT, WaaT, WbT, WhT);

  for (int ch = 0; ch < B_TOT / CHUNK; ch++){
    const float* in_c  = inputs + (size_t)ch * CHUNK * 16;
    const float* sku_c = sku    + (size_t)ch * CHUNK * 64;
    float* out_c       = outp   + (size_t)ch * CHUNK;

    hipLaunchKernelGGL(stage1_kernel, dim3(CHUNK/64), dim3(256), 0, stream,
                       in_c, sku_c, ln_g, ln_b, attnw, cps, wWo, WhT, agg, skub, skd);
    hipLaunchKernelGGL(gemm1, dim3(CHUNK/128*4), dim3(256), 0, stream,
                       agg, WahT, aggh);
    hipLaunchKernelGGL(mega2f, dim3(CHUNK/128*4), dim3(256), 0, stream,
                       aggh, WaaT, skub, WbT, Wo, part);
    hipLaunchKernelGGL(combine_kernel, dim3(CHUNK/256), dim3(256), 0, stream,
                       part, skd, out_c);
  }
}